// Round 9
// baseline (177.069 us; speedup 1.0000x reference)
//
#include <hip/hip_runtime.h>
#include <hip/hip_bf16.h>

// FC_KANLayer: B=6, T=1024, D_IN=256, D_OUT=512, NUM_GRIDS=8
// FUNC_LIST = [rbf, bs, dog, base, rbf, bs]
// f32 in/out; GEMMs via bf16 MFMA.
// R9: K1 = LN+basis + convert + packed-param transpose.
//     K2 = mega-kernel: dog (bf16-packed params, 32-t tiles, [d][t] LDS) first,
//          + no-LDS register GEMMs (spline, base). No split-K, no K3.

typedef short short8 __attribute__((ext_vector_type(8)));
typedef float floatx4 __attribute__((ext_vector_type(4)));

using bf16 = __hip_bfloat16;

#define LOG2E 1.44269504088896340736f

constexpr int Tn   = 1024;
constexpr int DIN  = 256;
constexpr int DOUT = 512;
constexpr int NG   = 8;
constexpr int KSP  = DIN * NG;            // 2048
constexpr float INV_DENOM = 7.0f / 3.0f;  // 1/DENOM, DENOM = 3/7

__device__ __forceinline__ unsigned short bf16bits(float v) {
    return __builtin_bit_cast(unsigned short, __float2bfloat16(v));
}
__device__ __forceinline__ float frombits(unsigned int u) {
    return __builtin_bit_cast(float, u);
}

// ================= K1 ========================================================
// [0,1536): LN+basis wave-per-row | [1536,2112): f32->bf16 convert (x8 vec)
// [2112,2144): dog-param transpose -> packed ro (bf16 r | bf16 o) + bf16 w
__global__ __launch_bounds__(256) void k1_kernel(
        const float* __restrict__ X,
        const float* __restrict__ w,
        const float* __restrict__ b,
        const float* __restrict__ grid_rbf,
        const float* __restrict__ grid_bs,
        const float* __restrict__ sw,
        const float* __restrict__ bw,
        const float* __restrict__ sc,
        const float* __restrict__ tr,
        bf16* __restrict__ Amat,            // [4096][2048]
        bf16* __restrict__ Sm,              // [1024][256]
        float* __restrict__ Xn2,            // [1024][256]
        bf16* __restrict__ swb,             // [512][2048]
        bf16* __restrict__ bwb,             // [512][256]
        unsigned int* __restrict__ roT,     // [256][512] packed bf16 (r,o)
        unsigned short* __restrict__ wnT) { // [256][512] bf16 (-bw)
    __shared__ float t1[64][65], t2[64][65];
    int tid = threadIdx.x, bid = blockIdx.x;

    if (bid >= 2112) {
        // ---- transpose role -------------------------------------------------
        int tb = bid - 2112;                  // 0..31
        int dout0 = (tb >> 2) * 64, din0 = (tb & 3) * 64;
        #pragma unroll
        for (int j = 0; j < 16; j++) {
            int idx = j * 256 + tid;
            int r = idx >> 6, c = idx & 63;
            float vs = sc[(dout0 + r) * DIN + din0 + c];
            float vt = tr[(dout0 + r) * DIN + din0 + c];
            float vb = bw[(dout0 + r) * DIN + din0 + c];
            float inv = 1.0f / vs;
            float o = -vt * inv;
            unsigned int packed = (unsigned int)bf16bits(inv)
                                | ((unsigned int)bf16bits(o) << 16);
            t1[r][c] = __builtin_bit_cast(float, packed);
            t2[r][c] = -vb;
        }
        __syncthreads();
        #pragma unroll
        for (int j = 0; j < 16; j++) {
            int idx = j * 256 + tid;
            int c = idx >> 6, r = idx & 63;   // consecutive tid -> consecutive r
            roT[(din0 + c) * DOUT + dout0 + r] = __builtin_bit_cast(unsigned int, t1[r][c]);
            wnT[(din0 + c) * DOUT + dout0 + r] = bf16bits(t2[r][c]);
        }
        return;
    }
    if (bid >= 1536) {
        // ---- convert role ---------------------------------------------------
        int e = ((bid - 1536) * 256 + tid) * 8;    // [0, 1179648)
        const float* src = (e < 1048576) ? (sw + e) : (bw + (e - 1048576));
        bf16* dst = (e < 1048576) ? (swb + e) : (bwb + (e - 1048576));
        float4 v0 = *(const float4*)src;
        float4 v1 = *(const float4*)(src + 4);
        short8 p;
        p[0] = __builtin_bit_cast(short, __float2bfloat16(v0.x));
        p[1] = __builtin_bit_cast(short, __float2bfloat16(v0.y));
        p[2] = __builtin_bit_cast(short, __float2bfloat16(v0.z));
        p[3] = __builtin_bit_cast(short, __float2bfloat16(v0.w));
        p[4] = __builtin_bit_cast(short, __float2bfloat16(v1.x));
        p[5] = __builtin_bit_cast(short, __float2bfloat16(v1.y));
        p[6] = __builtin_bit_cast(short, __float2bfloat16(v1.z));
        p[7] = __builtin_bit_cast(short, __float2bfloat16(v1.w));
        *(short8*)dst = p;
        return;
    }

    // ---- LN + basis role ----------------------------------------------------
    int wv = tid >> 6, lane = tid & 63;
    int row = bid * 4 + wv;              // b*1024 + t
    int batch = row >> 10, t = row & 1023;

    float x[4];
    #pragma unroll
    for (int j = 0; j < 4; j++) x[j] = X[(size_t)row * DIN + j * 64 + lane];
    float s = x[0] + x[1] + x[2] + x[3];
    float ss = x[0] * x[0] + x[1] * x[1] + x[2] * x[2] + x[3] * x[3];
    #pragma unroll
    for (int o = 1; o < 64; o <<= 1) {
        s  += __shfl_xor(s, o);
        ss += __shfl_xor(ss, o);
    }
    float mu = s * (1.0f / DIN);
    float rstd = rsqrtf(ss * (1.0f / DIN) - mu * mu + 1e-5f);

    float xn[4];
    #pragma unroll
    for (int j = 0; j < 4; j++) {
        int din = j * 64 + lane;
        xn[j] = (x[j] - mu) * rstd * w[din] + b[din];
    }

    if (batch == 2) {
        #pragma unroll
        for (int j = 0; j < 4; j++)
            Xn2[(size_t)t * DIN + j * 64 + lane] = xn[j];
    } else if (batch == 3) {
        #pragma unroll
        for (int j = 0; j < 4; j++) {
            float e = __builtin_amdgcn_exp2f(-xn[j] * LOG2E);
            float si = xn[j] * __builtin_amdgcn_rcpf(1.0f + e);
            Sm[(size_t)t * DIN + j * 64 + lane] = __float2bfloat16(si);
        }
    } else {
        int which = (batch == 0) ? 0 : (batch == 1) ? 1 : (batch == 4) ? 2 : 3;
        bool is_rbf = (batch == 0) || (batch == 4);
        #pragma unroll
        for (int j = 0; j < 4; j++) {
            float v = xn[j];
            float outv[NG];
            if (is_rbf) {
                #pragma unroll
                for (int g = 0; g < NG; g++) {
                    float d = (v - grid_rbf[g]) * INV_DENOM;
                    outv[g] = __builtin_amdgcn_exp2f(-d * d * LOG2E);
                }
            } else {
                float g[12];
                #pragma unroll
                for (int i = 0; i < 12; i++) g[i] = grid_bs[i];
                float ih = 1.0f / (g[1] - g[0]);
                float ihk[3] = {ih, ih * 0.5f, ih * (1.0f / 3.0f)};
                float bs_[11];
                #pragma unroll
                for (int i = 0; i < 11; i++)
                    bs_[i] = (v >= g[i] && v < g[i + 1]) ? 1.0f : 0.0f;
                #pragma unroll
                for (int k = 1; k <= 3; k++) {
                    float rk = ihk[k - 1];
                    #pragma unroll
                    for (int i = 0; i < 10; i++) {
                        if (i <= 10 - k) {
                            bs_[i] = (v - g[i]) * rk * bs_[i]
                                   + (g[i + k + 1] - v) * rk * bs_[i + 1];
                        }
                    }
                }
                #pragma unroll
                for (int gg = 0; gg < NG; gg++) outv[gg] = bs_[gg];
            }
            short8 pv;
            #pragma unroll
            for (int gg = 0; gg < NG; gg++)
                pv[gg] = __builtin_bit_cast(short, __float2bfloat16(outv[gg]));
            *(short8*)((short*)Amat + (size_t)(which * Tn + t) * KSP
                       + (size_t)(j * 64 + lane) * NG) = pv;
        }
    }
}

// -------- GEMM role: direct global fragment loads, register ping-pong --------
// C[M,512] = A[M,K] * W[512,K]^T ; wave tile 32x32 (2x2 MFMA frags); no LDS.
template <int K, int MODE>
__device__ __forceinline__ void gemm_role(const short* __restrict__ A,
                                          const short* __restrict__ Bw,
                                          float* __restrict__ out,
                                          int row0, int col0, int tid) {
    int wv = tid >> 6, lane = tid & 63;
    int m = lane & 15, q = lane >> 4;
    int wr = wv >> 1, wc = wv & 1;

    const short8* ap[2];
    const short8* bp[2];
    #pragma unroll
    for (int r = 0; r < 2; r++)
        ap[r] = (const short8*)(A + (size_t)(row0 + wr * 32 + r * 16 + m) * K);
    #pragma unroll
    for (int c = 0; c < 2; c++)
        bp[c] = (const short8*)(Bw + (size_t)(col0 + wc * 32 + c * 16 + m) * K);

    floatx4 acc[2][2];
    #pragma unroll
    for (int r = 0; r < 2; r++)
        #pragma unroll
        for (int c = 0; c < 2; c++) acc[r][c] = (floatx4)(0.0f);

    constexpr int STEPS = K / 32;         // short8 idx of step s = s*4 + q
    short8 a0[2], b0[2], a1[2], b1[2];
    #pragma unroll
    for (int r = 0; r < 2; r++) a0[r] = ap[r][q];
    #pragma unroll
    for (int c = 0; c < 2; c++) b0[c] = bp[c][q];

    for (int s = 0; s < STEPS; s += 2) {
        int i1 = (s + 1) * 4 + q;
        #pragma unroll
        for (int r = 0; r < 2; r++) a1[r] = ap[r][i1];
        #pragma unroll
        for (int c = 0; c < 2; c++) b1[c] = bp[c][i1];
        #pragma unroll
        for (int r = 0; r < 2; r++) {
            acc[r][0] = __builtin_amdgcn_mfma_f32_16x16x32_bf16(a0[r], b0[0], acc[r][0], 0, 0, 0);
            acc[r][1] = __builtin_amdgcn_mfma_f32_16x16x32_bf16(a0[r], b0[1], acc[r][1], 0, 0, 0);
        }
        if (s + 2 < STEPS) {
            int i2 = (s + 2) * 4 + q;
            #pragma unroll
            for (int r = 0; r < 2; r++) a0[r] = ap[r][i2];
            #pragma unroll
            for (int c = 0; c < 2; c++) b0[c] = bp[c][i2];
        }
        #pragma unroll
        for (int r = 0; r < 2; r++) {
            acc[r][0] = __builtin_amdgcn_mfma_f32_16x16x32_bf16(a1[r], b1[0], acc[r][0], 0, 0, 0);
            acc[r][1] = __builtin_amdgcn_mfma_f32_16x16x32_bf16(a1[r], b1[1], acc[r][1], 0, 0, 0);
        }
    }

    #pragma unroll
    for (int r = 0; r < 2; r++) {
        #pragma unroll
        for (int c = 0; c < 2; c++) {
            #pragma unroll
            for (int rr = 0; rr < 4; rr++) {
                int row = row0 + wr * 32 + r * 16 + q * 4 + rr;
                int col = col0 + wc * 32 + c * 16 + m;
                size_t off;
                if (MODE == 0) {
                    int which = row >> 10, t = row & 1023;
                    int batch = (which == 0) ? 0 : (which == 1) ? 1 : (which == 2) ? 4 : 5;
                    off = ((size_t)batch * Tn + t) * DOUT + col;
                } else {
                    off = ((size_t)3 * Tn + row) * DOUT + col;
                }
                out[off] = acc[r][c][rr];
            }
        }
    }
}

// ================= K2: mega-kernel ===========================================
// [0,256):   DoG, 64 dout x 32 t; packed bf16 params; x-tile [d][t] pad-36 LDS
// [256,768): spline GEMM 64x64 (mt=idx&63 -> XCD locality on A rows)
// [768,896): base GEMM 64x64, K=256
__global__ __launch_bounds__(256) void k2_kernel(const bf16* __restrict__ Amat,
                                                 const bf16* __restrict__ SWb,
                                                 const bf16* __restrict__ Sm,
                                                 const bf16* __restrict__ BWb,
                                                 const float* __restrict__ Xn2,
                                                 const unsigned int* __restrict__ roT,
                                                 const unsigned short* __restrict__ wnT,
                                                 float* __restrict__ out) {
    __shared__ float xs_[DIN * 36];   // 36 KiB, dog role only
    int bid = blockIdx.x, tid = threadIdx.x;

    if (bid < 256) {
        // ---- DoG role ------------------------------------------------------
        int dt = bid & 7, t0 = (bid >> 3) * 32;
        {
            int t_local = tid & 31;
            int d0 = (tid >> 5) * 32;          // 8 threads-groups x 32 d each
            #pragma unroll
            for (int i = 0; i < 8; i++) {
                float4 v = *(const float4*)&Xn2[(size_t)(t0 + t_local) * DIN + d0 + i * 4];
                xs_[(d0 + i * 4 + 0) * 36 + t_local] = v.x;
                xs_[(d0 + i * 4 + 1) * 36 + t_local] = v.y;
                xs_[(d0 + i * 4 + 2) * 36 + t_local] = v.z;
                xs_[(d0 + i * 4 + 3) * 36 + t_local] = v.w;
            }
        }
        __syncthreads();

        int dl = tid & 63, tg = tid >> 6;
        int dout = dt * 64 + dl;
        const float kC = -0.5f * LOG2E;
        float acc[8];
        #pragma unroll
        for (int j = 0; j < 8; j++) acc[j] = 0.0f;

        const unsigned int*   rop = roT + dout;
        const unsigned short* wnp = wnT + dout;
        #pragma unroll 2
        for (int d = 0; d < DIN; d++) {
            unsigned int ro = rop[d * DOUT];
            float r = frombits(ro << 16);
            float o = frombits(ro & 0xFFFF0000u);
            float w = frombits(((unsigned int)wnp[d * DOUT]) << 16);
            float4 xa = *(const float4*)&xs_[d * 36 + tg * 8];      // broadcast
            float4 xb = *(const float4*)&xs_[d * 36 + tg * 8 + 4];  // broadcast
            float xv[8] = {xa.x, xa.y, xa.z, xa.w, xb.x, xb.y, xb.z, xb.w};
            #pragma unroll
            for (int j = 0; j < 8; j++) {
                float xsv = fmaf(xv[j], r, o);
                float e = __builtin_amdgcn_exp2f(xsv * xsv * kC);
                acc[j] = fmaf(xsv * e, w, acc[j]);
            }
        }
        size_t base = (size_t)2 * Tn * DOUT + (size_t)(t0 + tg * 8) * DOUT + dout;
        #pragma unroll
        for (int j = 0; j < 8; j++) out[base + (size_t)j * DOUT] = acc[j];
    } else if (bid < 768) {
        int idx = bid - 256;
        int mt = idx & 63, nt = idx >> 6;
        gemm_role<KSP, 0>((const short*)Amat, (const short*)SWb, out,
                          mt * 64, nt * 64, tid);
    } else {
        int idx = bid - 768;
        int mt = idx >> 3, nt = idx & 7;
        gemm_role<DIN, 1>((const short*)Sm, (const short*)BWb, out,
                          mt * 64, nt * 64, tid);
    }
}

extern "C" void kernel_launch(void* const* d_in, const int* in_sizes, int n_in,
                              void* d_out, int out_size, void* d_ws, size_t ws_size,
                              hipStream_t stream) {
    const float* X        = (const float*)d_in[0];
    const float* ln_w     = (const float*)d_in[1];
    const float* ln_b     = (const float*)d_in[2];
    const float* base_w   = (const float*)d_in[3];
    const float* spline_w = (const float*)d_in[4];
    const float* scale    = (const float*)d_in[5];
    const float* transl   = (const float*)d_in[6];
    const float* grid_rbf = (const float*)d_in[7];
    const float* grid_bs  = (const float*)d_in[8];
    float* out = (float*)d_out;

    char* ws = (char*)d_ws;
    bf16*  Amat = (bf16*)ws;                                   // 16 MiB   [4096][2048]
    bf16*  SWb  = (bf16*)(ws + 16777216);                      // 2 MiB    [512][2048]
    bf16*  BWb  = (bf16*)(ws + 18874368);                      // 0.25 MiB [512][256]
    bf16*  Sm   = (bf16*)(ws + 19136512);                      // 0.5 MiB  [1024][256]
    float* Xn2  = (float*)(ws + 19660800);                     // 1 MiB    [1024][256]
    unsigned int*   roT = (unsigned int*)(ws + 20709376);      // 0.5 MiB  [256][512]
    unsigned short* wnT = (unsigned short*)(ws + 21233664);    // 0.25 MiB [256][512]

    k1_kernel<<<2144, 256, 0, stream>>>(X, ln_w, ln_b, grid_rbf, grid_bs,
                                        spline_w, base_w, scale, transl,
                                        Amat, Sm, Xn2, SWb, BWb, roT, wnT);
    k2_kernel<<<896, 256, 0, stream>>>(Amat, SWb, Sm, BWb, Xn2, roT, wnT, out);
}

// Round 10
// 128.931 us; speedup vs baseline: 1.3734x; 1.3734x over previous
//
#include <hip/hip_runtime.h>
#include <hip/hip_bf16.h>

// FC_KANLayer: B=6, T=1024, D_IN=256, D_OUT=512, NUM_GRIDS=8
// FUNC_LIST = [rbf, bs, dog, base, rbf, bs]
// f32 in/out; GEMMs via bf16 MFMA.
// R10 = verified-best recombination:
//   K1: LN+basis (wave/row) + convert(x8) + packed-param transpose (32x32, 8.4KB LDS)
//   K2: dog (512 blocks, packed bf16 params, [t][d] LDS, b128 broadcast)
//       + spline GEMM split-K=2 (R8 LDS-dbuf core, A-locality bid order)
//       + base GEMM. All roles 16KB LDS.
//   K3: split-K reduce.

typedef short short8 __attribute__((ext_vector_type(8)));
typedef float floatx4 __attribute__((ext_vector_type(4)));

using bf16 = __hip_bfloat16;

#define LOG2E 1.44269504088896340736f

constexpr int Tn   = 1024;
constexpr int DIN  = 256;
constexpr int DOUT = 512;
constexpr int NG   = 8;
constexpr int KSP  = DIN * NG;            // 2048
constexpr float INV_DENOM = 7.0f / 3.0f;  // 1/DENOM, DENOM = 3/7

__device__ __forceinline__ unsigned int bf16bits(float v) {
    return (unsigned int)__builtin_bit_cast(unsigned short, __float2bfloat16(v));
}
__device__ __forceinline__ float frombits(unsigned int u) {
    return __builtin_bit_cast(float, u);
}

// ================= K1 ========================================================
// [0,1536): LN+basis wave-per-row | [1536,2112): f32->bf16 convert (x8 vec)
// [2112,2240): dog-param transpose-pack, 32x32 tiles
__global__ __launch_bounds__(256) void k1_kernel(
        const float* __restrict__ X,
        const float* __restrict__ w,
        const float* __restrict__ b,
        const float* __restrict__ grid_rbf,
        const float* __restrict__ grid_bs,
        const float* __restrict__ sw,
        const float* __restrict__ bw,
        const float* __restrict__ sc,
        const float* __restrict__ tr,
        bf16* __restrict__ Amat,            // [4096][2048]
        bf16* __restrict__ Sm,              // [1024][256]
        float* __restrict__ Xn2,            // [1024][256]
        bf16* __restrict__ swb,             // [512][2048]
        bf16* __restrict__ bwb,             // [512][256]
        unsigned int* __restrict__ roT,     // [256][512] packed bf16 (r,o)
        unsigned short* __restrict__ wnT) { // [256][512] bf16 (-bw)
    __shared__ float u1[32][33], u2[32][33];
    int tid = threadIdx.x, bid = blockIdx.x;

    if (bid >= 2112) {
        // ---- transpose-pack role -------------------------------------------
        int tb = bid - 2112;                  // 0..127
        int dout0 = (tb >> 3) * 32, din0 = (tb & 7) * 32;
        #pragma unroll
        for (int p = 0; p < 4; p++) {
            int idx = p * 256 + tid;
            int r = idx >> 5, c = idx & 31;
            float vs = sc[(dout0 + r) * DIN + din0 + c];
            float vt = tr[(dout0 + r) * DIN + din0 + c];
            float vb = bw[(dout0 + r) * DIN + din0 + c];
            float inv = 1.0f / vs;
            unsigned int packed = bf16bits(inv) | (bf16bits(-vt * inv) << 16);
            u1[r][c] = __builtin_bit_cast(float, packed);
            u2[r][c] = -vb;
        }
        __syncthreads();
        #pragma unroll
        for (int p = 0; p < 4; p++) {
            int idx = p * 256 + tid;
            int c = idx >> 5, r = idx & 31;   // consecutive tid -> consecutive r
            roT[(din0 + c) * DOUT + dout0 + r] = __builtin_bit_cast(unsigned int, u1[r][c]);
            wnT[(din0 + c) * DOUT + dout0 + r] = (unsigned short)bf16bits(u2[r][c]);
        }
        return;
    }
    if (bid >= 1536) {
        // ---- convert role ---------------------------------------------------
        int e = ((bid - 1536) * 256 + tid) * 8;    // [0, 1179648)
        const float* src = (e < 1048576) ? (sw + e) : (bw + (e - 1048576));
        bf16* dst = (e < 1048576) ? (swb + e) : (bwb + (e - 1048576));
        float4 v0 = *(const float4*)src;
        float4 v1 = *(const float4*)(src + 4);
        short8 p;
        p[0] = __builtin_bit_cast(short, __float2bfloat16(v0.x));
        p[1] = __builtin_bit_cast(short, __float2bfloat16(v0.y));
        p[2] = __builtin_bit_cast(short, __float2bfloat16(v0.z));
        p[3] = __builtin_bit_cast(short, __float2bfloat16(v0.w));
        p[4] = __builtin_bit_cast(short, __float2bfloat16(v1.x));
        p[5] = __builtin_bit_cast(short, __float2bfloat16(v1.y));
        p[6] = __builtin_bit_cast(short, __float2bfloat16(v1.z));
        p[7] = __builtin_bit_cast(short, __float2bfloat16(v1.w));
        *(short8*)dst = p;
        return;
    }

    // ---- LN + basis role ----------------------------------------------------
    int wv = tid >> 6, lane = tid & 63;
    int row = bid * 4 + wv;              // b*1024 + t
    int batch = row >> 10, t = row & 1023;

    float x[4];
    #pragma unroll
    for (int j = 0; j < 4; j++) x[j] = X[(size_t)row * DIN + j * 64 + lane];
    float s = x[0] + x[1] + x[2] + x[3];
    float ss = x[0] * x[0] + x[1] * x[1] + x[2] * x[2] + x[3] * x[3];
    #pragma unroll
    for (int o = 1; o < 64; o <<= 1) {
        s  += __shfl_xor(s, o);
        ss += __shfl_xor(ss, o);
    }
    float mu = s * (1.0f / DIN);
    float rstd = rsqrtf(ss * (1.0f / DIN) - mu * mu + 1e-5f);

    float xn[4];
    #pragma unroll
    for (int j = 0; j < 4; j++) {
        int din = j * 64 + lane;
        xn[j] = (x[j] - mu) * rstd * w[din] + b[din];
    }

    if (batch == 2) {
        #pragma unroll
        for (int j = 0; j < 4; j++)
            Xn2[(size_t)t * DIN + j * 64 + lane] = xn[j];
    } else if (batch == 3) {
        #pragma unroll
        for (int j = 0; j < 4; j++) {
            float e = __builtin_amdgcn_exp2f(-xn[j] * LOG2E);
            float si = xn[j] * __builtin_amdgcn_rcpf(1.0f + e);
            Sm[(size_t)t * DIN + j * 64 + lane] = __float2bfloat16(si);
        }
    } else {
        int which = (batch == 0) ? 0 : (batch == 1) ? 1 : (batch == 4) ? 2 : 3;
        bool is_rbf = (batch == 0) || (batch == 4);
        #pragma unroll
        for (int j = 0; j < 4; j++) {
            float v = xn[j];
            float outv[NG];
            if (is_rbf) {
                #pragma unroll
                for (int g = 0; g < NG; g++) {
                    float d = (v - grid_rbf[g]) * INV_DENOM;
                    outv[g] = __builtin_amdgcn_exp2f(-d * d * LOG2E);
                }
            } else {
                float g[12];
                #pragma unroll
                for (int i = 0; i < 12; i++) g[i] = grid_bs[i];
                float ih = 1.0f / (g[1] - g[0]);
                float ihk[3] = {ih, ih * 0.5f, ih * (1.0f / 3.0f)};
                float bs_[11];
                #pragma unroll
                for (int i = 0; i < 11; i++)
                    bs_[i] = (v >= g[i] && v < g[i + 1]) ? 1.0f : 0.0f;
                #pragma unroll
                for (int k = 1; k <= 3; k++) {
                    float rk = ihk[k - 1];
                    #pragma unroll
                    for (int i = 0; i < 10; i++) {
                        if (i <= 10 - k) {
                            bs_[i] = (v - g[i]) * rk * bs_[i]
                                   + (g[i + k + 1] - v) * rk * bs_[i + 1];
                        }
                    }
                }
                #pragma unroll
                for (int gg = 0; gg < NG; gg++) outv[gg] = bs_[gg];
            }
            short8 pv;
            #pragma unroll
            for (int gg = 0; gg < NG; gg++)
                pv[gg] = __builtin_bit_cast(short, __float2bfloat16(outv[gg]));
            *(short8*)((short*)Amat + (size_t)(which * Tn + t) * KSP
                       + (size_t)(j * 64 + lane) * NG) = pv;
        }
    }
}

// ---------------- GEMM core: 64x64 tile, BK=32, dbuf LDS, XOR-swizzled -------
// (R8-verified) LDS slot (row ri, chunk cs) holds k-chunk cs ^ ((ri>>1)&3).
template <int KS>
__device__ __forceinline__ void gemm_core(const short* __restrict__ A,
                                          const short* __restrict__ Bw,
                                          int row0, int col0, int kbase, int iters,
                                          int tid, char* smem, floatx4 acc[2][2]) {
    short* ldsA = (short*)smem;            // [2][64][32] = 8 KiB
    short* ldsB = (short*)(smem + 8192);   // [2][64][32] = 8 KiB
    int wv = tid >> 6, lane = tid & 63;
    int r16 = lane >> 2, cs = lane & 3;
    int cg = cs ^ ((r16 >> 1) & 3);
    const short* gA = A  + (size_t)(row0 + wv * 16 + r16) * KS + kbase + cg * 8;
    const short* gB = Bw + (size_t)(col0 + wv * 16 + r16) * KS + kbase + cg * 8;

    int m = lane & 15, q = lane >> 4;
    int wr = wv >> 1, wc = wv & 1;
    int ra0 = wr * 32 + m, ra1 = ra0 + 16;
    int rb0 = wc * 32 + m, rb1 = rb0 + 16;
    int oA0 = ra0 * 32 + (q ^ ((ra0 >> 1) & 3)) * 8;
    int oA1 = ra1 * 32 + (q ^ ((ra1 >> 1) & 3)) * 8;
    int oB0 = rb0 * 32 + (q ^ ((rb0 >> 1) & 3)) * 8;
    int oB1 = rb1 * 32 + (q ^ ((rb1 >> 1) & 3)) * 8;

    __builtin_amdgcn_global_load_lds(
        (const __attribute__((address_space(1))) void*)gA,
        (__attribute__((address_space(3))) void*)(ldsA + wv * 512), 16, 0, 0);
    __builtin_amdgcn_global_load_lds(
        (const __attribute__((address_space(1))) void*)gB,
        (__attribute__((address_space(3))) void*)(ldsB + wv * 512), 16, 0, 0);

    for (int i = 0; i < iters; i++) {
        int cur = i & 1;
        __syncthreads();
        if (i + 1 < iters) {
            int nxt = cur ^ 1, kof = (i + 1) * 32;
            __builtin_amdgcn_global_load_lds(
                (const __attribute__((address_space(1))) void*)(gA + kof),
                (__attribute__((address_space(3))) void*)(ldsA + nxt * 2048 + wv * 512),
                16, 0, 0);
            __builtin_amdgcn_global_load_lds(
                (const __attribute__((address_space(1))) void*)(gB + kof),
                (__attribute__((address_space(3))) void*)(ldsB + nxt * 2048 + wv * 512),
                16, 0, 0);
        }
        const short* bA = ldsA + cur * 2048;
        const short* bB = ldsB + cur * 2048;
        short8 a0 = *(const short8*)(bA + oA0);
        short8 a1 = *(const short8*)(bA + oA1);
        short8 b0 = *(const short8*)(bB + oB0);
        short8 b1 = *(const short8*)(bB + oB1);
        acc[0][0] = __builtin_amdgcn_mfma_f32_16x16x32_bf16(a0, b0, acc[0][0], 0, 0, 0);
        acc[0][1] = __builtin_amdgcn_mfma_f32_16x16x32_bf16(a0, b1, acc[0][1], 0, 0, 0);
        acc[1][0] = __builtin_amdgcn_mfma_f32_16x16x32_bf16(a1, b0, acc[1][0], 0, 0, 0);
        acc[1][1] = __builtin_amdgcn_mfma_f32_16x16x32_bf16(a1, b1, acc[1][1], 0, 0, 0);
    }
}

// ================= K2: heterogeneous mega-kernel =============================
// [0,512):    DoG, 64 dout x 16 t, packed bf16 params, [t][d] LDS (16 KiB)
// [512,1536): spline GEMM 64x64 split-K=2 (nt innermost -> A-slice locality)
// [1536,1664): base GEMM 64x64, K=256
__global__ __launch_bounds__(256) void k2_kernel(const bf16* __restrict__ Amat,
                                                 const bf16* __restrict__ SWb,
                                                 const bf16* __restrict__ Sm,
                                                 const bf16* __restrict__ BWb,
                                                 const float* __restrict__ Xn2,
                                                 const unsigned int* __restrict__ roT,
                                                 const unsigned short* __restrict__ wnT,
                                                 float* __restrict__ P0,
                                                 float* __restrict__ P1,
                                                 float* __restrict__ out) {
    __shared__ alignas(16) char smem[16384];
    int bid = blockIdx.x, tid = threadIdx.x;

    if (bid < 512) {
        // ---- DoG role ------------------------------------------------------
        int dt = bid & 7, t0 = (bid >> 3) * 16;
        float* xs_ = (float*)smem;         // [16][256]
        #pragma unroll
        for (int p = 0; p < 4; p++) {
            int flat = p * 1024 + tid * 4;
            *(float4*)&xs_[flat] = *(const float4*)&Xn2[(size_t)t0 * DIN + flat];
        }
        __syncthreads();

        int dl = tid & 63, tg = tid >> 6;   // 4 t per lane
        int dout = dt * 64 + dl;
        const float kC = -0.5f * LOG2E;
        float acc[4] = {0.f, 0.f, 0.f, 0.f};
        const unsigned int*   rop = roT + dout;
        const unsigned short* wnp = wnT + dout;

        for (int d = 0; d < DIN; d += 4) {
            float rr[4], oo[4], ww[4];
            #pragma unroll
            for (int k = 0; k < 4; k++) {
                unsigned int ro = rop[(d + k) * DOUT];
                rr[k] = frombits(ro << 16);
                oo[k] = frombits(ro & 0xFFFF0000u);
                ww[k] = frombits(((unsigned int)wnp[(d + k) * DOUT]) << 16);
            }
            #pragma unroll
            for (int j = 0; j < 4; j++) {   // t = tg*4 + j
                float4 xv = *(const float4*)&xs_[(tg * 4 + j) * DIN + d]; // broadcast
                float xs4[4] = {xv.x, xv.y, xv.z, xv.w};
                #pragma unroll
                for (int k = 0; k < 4; k++) {
                    float z = fmaf(xs4[k], rr[k], oo[k]);
                    float e = __builtin_amdgcn_exp2f(z * z * kC);
                    acc[j] = fmaf(z * e, ww[k], acc[j]);
                }
            }
        }
        size_t base = (size_t)2 * Tn * DOUT + (size_t)(t0 + tg * 4) * DOUT + dout;
        #pragma unroll
        for (int j = 0; j < 4; j++) out[base + (size_t)j * DOUT] = acc[j];
    } else if (bid < 1536) {
        // ---- spline GEMM role (split-K=2) ----------------------------------
        int idx = bid - 512;
        int mt = idx >> 4, kc = (idx >> 3) & 1, nt = idx & 7;
        int row0 = mt * 64, col0 = nt * 64;
        floatx4 acc[2][2];
        #pragma unroll
        for (int r = 0; r < 2; r++)
            #pragma unroll
            for (int c = 0; c < 2; c++) acc[r][c] = (floatx4)(0.0f);
        gemm_core<KSP>((const short*)Amat, (const short*)SWb,
                       row0, col0, kc * 1024, 32, tid, smem, acc);
        float* P = kc ? P1 : P0;
        int wv = tid >> 6, lane = tid & 63;
        int m = lane & 15, q = lane >> 4;
        int wr = wv >> 1, wc = wv & 1;
        #pragma unroll
        for (int r = 0; r < 2; r++)
            #pragma unroll
            for (int c = 0; c < 2; c++)
                #pragma unroll
                for (int rr = 0; rr < 4; rr++) {
                    int row = row0 + wr * 32 + r * 16 + q * 4 + rr;
                    int col = col0 + wc * 32 + c * 16 + m;
                    P[(size_t)row * DOUT + col] = acc[r][c][rr];
                }
    } else {
        // ---- base GEMM role ------------------------------------------------
        int idx = bid - 1536;
        int mt = idx >> 3, nt = idx & 7;
        int row0 = mt * 64, col0 = nt * 64;
        floatx4 acc[2][2];
        #pragma unroll
        for (int r = 0; r < 2; r++)
            #pragma unroll
            for (int c = 0; c < 2; c++) acc[r][c] = (floatx4)(0.0f);
        gemm_core<DIN>((const short*)Sm, (const short*)BWb,
                       row0, col0, 0, 8, tid, smem, acc);
        int wv = tid >> 6, lane = tid & 63;
        int m = lane & 15, q = lane >> 4;
        int wr = wv >> 1, wc = wv & 1;
        #pragma unroll
        for (int r = 0; r < 2; r++)
            #pragma unroll
            for (int c = 0; c < 2; c++)
                #pragma unroll
                for (int rr = 0; rr < 4; rr++) {
                    int row = row0 + wr * 32 + r * 16 + q * 4 + rr;
                    int col = col0 + wc * 32 + c * 16 + m;
                    out[((size_t)3 * Tn + row) * DOUT + col] = acc[r][c][rr];
                }
    }
}

// ================= K3: split-K reduce (P0+P1 -> out, spline batches) =========
__global__ __launch_bounds__(256) void k3_kernel(const float* __restrict__ P0,
                                                 const float* __restrict__ P1,
                                                 float* __restrict__ out) {
    int t4 = blockIdx.x * 256 + threadIdx.x;    // [0, 131072)
    #pragma unroll
    for (int k = 0; k < 4; k++) {
        int i4 = t4 + k * 131072;               // float4 index, [0, 524288)
        int row = i4 >> 7, c4 = i4 & 127;
        int which = row >> 10, t = row & 1023;
        int batch = (which == 0) ? 0 : (which == 1) ? 1 : (which == 2) ? 4 : 5;
        float4 a = *(const float4*)(P0 + (size_t)i4 * 4);
        float4 b = *(const float4*)(P1 + (size_t)i4 * 4);
        float4 s = make_float4(a.x + b.x, a.y + b.y, a.z + b.z, a.w + b.w);
        *(float4*)&out[((size_t)batch * Tn + t) * DOUT + c4 * 4] = s;
    }
}

extern "C" void kernel_launch(void* const* d_in, const int* in_sizes, int n_in,
                              void* d_out, int out_size, void* d_ws, size_t ws_size,
                              hipStream_t stream) {
    const float* X        = (const float*)d_in[0];
    const float* ln_w     = (const float*)d_in[1];
    const float* ln_b     = (const float*)d_in[2];
    const float* base_w   = (const float*)d_in[3];
    const float* spline_w = (const float*)d_in[4];
    const float* scale    = (const float*)d_in[5];
    const float* transl   = (const float*)d_in[6];
    const float* grid_rbf = (const float*)d_in[7];
    const float* grid_bs  = (const float*)d_in[8];
    float* out = (float*)d_out;

    char* ws = (char*)d_ws;
    bf16*  Amat = (bf16*)ws;                                   // 16 MiB   [4096][2048]
    bf16*  SWb  = (bf16*)(ws + 16777216);                      // 2 MiB    [512][2048]
    bf16*  BWb  = (bf16*)(ws + 18874368);                      // 0.25 MiB [512][256]
    bf16*  Sm   = (bf16*)(ws + 19136512);                      // 0.5 MiB  [1024][256]
    float* Xn2  = (float*)(ws + 19660800);                     // 1 MiB    [1024][256]
    unsigned int*   roT = (unsigned int*)(ws + 20709376);      // 0.5 MiB  [256][512]
    unsigned short* wnT = (unsigned short*)(ws + 21233664);    // 0.25 MiB [256][512]
    float* P0   = (float*)(ws + 22282240);                     // 8 MiB    [4096][512]
    float* P1   = (float*)(ws + 30670848);                     // 8 MiB

    k1_kernel<<<2240, 256, 0, stream>>>(X, ln_w, ln_b, grid_rbf, grid_bs,
                                        spline_w, base_w, scale, transl,
                                        Amat, Sm, Xn2, SWb, BWb, roT, wnT);
    k2_kernel<<<1664, 256, 0, stream>>>(Amat, SWb, Sm, BWb, Xn2, roT, wnT,
                                        P0, P1, out);
    k3_kernel<<<512, 256, 0, stream>>>(P0, P1, out);
}

// Round 11
// 127.969 us; speedup vs baseline: 1.3837x; 1.0075x over previous
//
#include <hip/hip_runtime.h>
#include <hip/hip_bf16.h>

// FC_KANLayer: B=6, T=1024, D_IN=256, D_OUT=512, NUM_GRIDS=8
// FUNC_LIST = [rbf, bs, dog, base, rbf, bs]
// f32 in/out; GEMMs via bf16 MFMA.
// R11 = R10 + (a) XCD-correct spline bid order (nt in slow dim -> A-slice
// fetched once per XCD; R7-verified placement), (b) bf16 split-K partials.

typedef short short8 __attribute__((ext_vector_type(8)));
typedef float floatx4 __attribute__((ext_vector_type(4)));

using bf16 = __hip_bfloat16;

#define LOG2E 1.44269504088896340736f

constexpr int Tn   = 1024;
constexpr int DIN  = 256;
constexpr int DOUT = 512;
constexpr int NG   = 8;
constexpr int KSP  = DIN * NG;            // 2048
constexpr float INV_DENOM = 7.0f / 3.0f;  // 1/DENOM, DENOM = 3/7

__device__ __forceinline__ unsigned int bf16bits(float v) {
    return (unsigned int)__builtin_bit_cast(unsigned short, __float2bfloat16(v));
}
__device__ __forceinline__ float frombits(unsigned int u) {
    return __builtin_bit_cast(float, u);
}

// ================= K1 ========================================================
// [0,1536): LN+basis wave-per-row | [1536,2112): f32->bf16 convert (x8 vec)
// [2112,2240): dog-param transpose-pack, 32x32 tiles
__global__ __launch_bounds__(256) void k1_kernel(
        const float* __restrict__ X,
        const float* __restrict__ w,
        const float* __restrict__ b,
        const float* __restrict__ grid_rbf,
        const float* __restrict__ grid_bs,
        const float* __restrict__ sw,
        const float* __restrict__ bw,
        const float* __restrict__ sc,
        const float* __restrict__ tr,
        bf16* __restrict__ Amat,            // [4096][2048]
        bf16* __restrict__ Sm,              // [1024][256]
        float* __restrict__ Xn2,            // [1024][256]
        bf16* __restrict__ swb,             // [512][2048]
        bf16* __restrict__ bwb,             // [512][256]
        unsigned int* __restrict__ roT,     // [256][512] packed bf16 (r,o)
        unsigned short* __restrict__ wnT) { // [256][512] bf16 (-bw)
    __shared__ float u1[32][33], u2[32][33];
    int tid = threadIdx.x, bid = blockIdx.x;

    if (bid >= 2112) {
        // ---- transpose-pack role -------------------------------------------
        int tb = bid - 2112;                  // 0..127
        int dout0 = (tb >> 3) * 32, din0 = (tb & 7) * 32;
        #pragma unroll
        for (int p = 0; p < 4; p++) {
            int idx = p * 256 + tid;
            int r = idx >> 5, c = idx & 31;
            float vs = sc[(dout0 + r) * DIN + din0 + c];
            float vt = tr[(dout0 + r) * DIN + din0 + c];
            float vb = bw[(dout0 + r) * DIN + din0 + c];
            float inv = 1.0f / vs;
            unsigned int packed = bf16bits(inv) | (bf16bits(-vt * inv) << 16);
            u1[r][c] = __builtin_bit_cast(float, packed);
            u2[r][c] = -vb;
        }
        __syncthreads();
        #pragma unroll
        for (int p = 0; p < 4; p++) {
            int idx = p * 256 + tid;
            int c = idx >> 5, r = idx & 31;   // consecutive tid -> consecutive r
            roT[(din0 + c) * DOUT + dout0 + r] = __builtin_bit_cast(unsigned int, u1[r][c]);
            wnT[(din0 + c) * DOUT + dout0 + r] = (unsigned short)bf16bits(u2[r][c]);
        }
        return;
    }
    if (bid >= 1536) {
        // ---- convert role ---------------------------------------------------
        int e = ((bid - 1536) * 256 + tid) * 8;    // [0, 1179648)
        const float* src = (e < 1048576) ? (sw + e) : (bw + (e - 1048576));
        bf16* dst = (e < 1048576) ? (swb + e) : (bwb + (e - 1048576));
        float4 v0 = *(const float4*)src;
        float4 v1 = *(const float4*)(src + 4);
        short8 p;
        p[0] = __builtin_bit_cast(short, __float2bfloat16(v0.x));
        p[1] = __builtin_bit_cast(short, __float2bfloat16(v0.y));
        p[2] = __builtin_bit_cast(short, __float2bfloat16(v0.z));
        p[3] = __builtin_bit_cast(short, __float2bfloat16(v0.w));
        p[4] = __builtin_bit_cast(short, __float2bfloat16(v1.x));
        p[5] = __builtin_bit_cast(short, __float2bfloat16(v1.y));
        p[6] = __builtin_bit_cast(short, __float2bfloat16(v1.z));
        p[7] = __builtin_bit_cast(short, __float2bfloat16(v1.w));
        *(short8*)dst = p;
        return;
    }

    // ---- LN + basis role ----------------------------------------------------
    int wv = tid >> 6, lane = tid & 63;
    int row = bid * 4 + wv;              // b*1024 + t
    int batch = row >> 10, t = row & 1023;

    float x[4];
    #pragma unroll
    for (int j = 0; j < 4; j++) x[j] = X[(size_t)row * DIN + j * 64 + lane];
    float s = x[0] + x[1] + x[2] + x[3];
    float ss = x[0] * x[0] + x[1] * x[1] + x[2] * x[2] + x[3] * x[3];
    #pragma unroll
    for (int o = 1; o < 64; o <<= 1) {
        s  += __shfl_xor(s, o);
        ss += __shfl_xor(ss, o);
    }
    float mu = s * (1.0f / DIN);
    float rstd = rsqrtf(ss * (1.0f / DIN) - mu * mu + 1e-5f);

    float xn[4];
    #pragma unroll
    for (int j = 0; j < 4; j++) {
        int din = j * 64 + lane;
        xn[j] = (x[j] - mu) * rstd * w[din] + b[din];
    }

    if (batch == 2) {
        #pragma unroll
        for (int j = 0; j < 4; j++)
            Xn2[(size_t)t * DIN + j * 64 + lane] = xn[j];
    } else if (batch == 3) {
        #pragma unroll
        for (int j = 0; j < 4; j++) {
            float e = __builtin_amdgcn_exp2f(-xn[j] * LOG2E);
            float si = xn[j] * __builtin_amdgcn_rcpf(1.0f + e);
            Sm[(size_t)t * DIN + j * 64 + lane] = __float2bfloat16(si);
        }
    } else {
        int which = (batch == 0) ? 0 : (batch == 1) ? 1 : (batch == 4) ? 2 : 3;
        bool is_rbf = (batch == 0) || (batch == 4);
        #pragma unroll
        for (int j = 0; j < 4; j++) {
            float v = xn[j];
            float outv[NG];
            if (is_rbf) {
                #pragma unroll
                for (int g = 0; g < NG; g++) {
                    float d = (v - grid_rbf[g]) * INV_DENOM;
                    outv[g] = __builtin_amdgcn_exp2f(-d * d * LOG2E);
                }
            } else {
                float g[12];
                #pragma unroll
                for (int i = 0; i < 12; i++) g[i] = grid_bs[i];
                float ih = 1.0f / (g[1] - g[0]);
                float ihk[3] = {ih, ih * 0.5f, ih * (1.0f / 3.0f)};
                float bs_[11];
                #pragma unroll
                for (int i = 0; i < 11; i++)
                    bs_[i] = (v >= g[i] && v < g[i + 1]) ? 1.0f : 0.0f;
                #pragma unroll
                for (int k = 1; k <= 3; k++) {
                    float rk = ihk[k - 1];
                    #pragma unroll
                    for (int i = 0; i < 10; i++) {
                        if (i <= 10 - k) {
                            bs_[i] = (v - g[i]) * rk * bs_[i]
                                   + (g[i + k + 1] - v) * rk * bs_[i + 1];
                        }
                    }
                }
                #pragma unroll
                for (int gg = 0; gg < NG; gg++) outv[gg] = bs_[gg];
            }
            short8 pv;
            #pragma unroll
            for (int gg = 0; gg < NG; gg++)
                pv[gg] = __builtin_bit_cast(short, __float2bfloat16(outv[gg]));
            *(short8*)((short*)Amat + (size_t)(which * Tn + t) * KSP
                       + (size_t)(j * 64 + lane) * NG) = pv;
        }
    }
}

// ---------------- GEMM core: 64x64 tile, BK=32, dbuf LDS, XOR-swizzled -------
template <int KS>
__device__ __forceinline__ void gemm_core(const short* __restrict__ A,
                                          const short* __restrict__ Bw,
                                          int row0, int col0, int kbase, int iters,
                                          int tid, char* smem, floatx4 acc[2][2]) {
    short* ldsA = (short*)smem;            // [2][64][32] = 8 KiB
    short* ldsB = (short*)(smem + 8192);   // [2][64][32] = 8 KiB
    int wv = tid >> 6, lane = tid & 63;
    int r16 = lane >> 2, cs = lane & 3;
    int cg = cs ^ ((r16 >> 1) & 3);
    const short* gA = A  + (size_t)(row0 + wv * 16 + r16) * KS + kbase + cg * 8;
    const short* gB = Bw + (size_t)(col0 + wv * 16 + r16) * KS + kbase + cg * 8;

    int m = lane & 15, q = lane >> 4;
    int wr = wv >> 1, wc = wv & 1;
    int ra0 = wr * 32 + m, ra1 = ra0 + 16;
    int rb0 = wc * 32 + m, rb1 = rb0 + 16;
    int oA0 = ra0 * 32 + (q ^ ((ra0 >> 1) & 3)) * 8;
    int oA1 = ra1 * 32 + (q ^ ((ra1 >> 1) & 3)) * 8;
    int oB0 = rb0 * 32 + (q ^ ((rb0 >> 1) & 3)) * 8;
    int oB1 = rb1 * 32 + (q ^ ((rb1 >> 1) & 3)) * 8;

    __builtin_amdgcn_global_load_lds(
        (const __attribute__((address_space(1))) void*)gA,
        (__attribute__((address_space(3))) void*)(ldsA + wv * 512), 16, 0, 0);
    __builtin_amdgcn_global_load_lds(
        (const __attribute__((address_space(1))) void*)gB,
        (__attribute__((address_space(3))) void*)(ldsB + wv * 512), 16, 0, 0);

    for (int i = 0; i < iters; i++) {
        int cur = i & 1;
        __syncthreads();
        if (i + 1 < iters) {
            int nxt = cur ^ 1, kof = (i + 1) * 32;
            __builtin_amdgcn_global_load_lds(
                (const __attribute__((address_space(1))) void*)(gA + kof),
                (__attribute__((address_space(3))) void*)(ldsA + nxt * 2048 + wv * 512),
                16, 0, 0);
            __builtin_amdgcn_global_load_lds(
                (const __attribute__((address_space(1))) void*)(gB + kof),
                (__attribute__((address_space(3))) void*)(ldsB + nxt * 2048 + wv * 512),
                16, 0, 0);
        }
        const short* bA = ldsA + cur * 2048;
        const short* bB = ldsB + cur * 2048;
        short8 a0 = *(const short8*)(bA + oA0);
        short8 a1 = *(const short8*)(bA + oA1);
        short8 b0 = *(const short8*)(bB + oB0);
        short8 b1 = *(const short8*)(bB + oB1);
        acc[0][0] = __builtin_amdgcn_mfma_f32_16x16x32_bf16(a0, b0, acc[0][0], 0, 0, 0);
        acc[0][1] = __builtin_amdgcn_mfma_f32_16x16x32_bf16(a0, b1, acc[0][1], 0, 0, 0);
        acc[1][0] = __builtin_amdgcn_mfma_f32_16x16x32_bf16(a1, b0, acc[1][0], 0, 0, 0);
        acc[1][1] = __builtin_amdgcn_mfma_f32_16x16x32_bf16(a1, b1, acc[1][1], 0, 0, 0);
    }
}

// ================= K2: heterogeneous mega-kernel =============================
// [0,512):    DoG, 64 dout x 16 t, packed bf16 params, [t][d] LDS (16 KiB)
// [512,1536): spline GEMM 64x64 split-K=2; bid = 512 + nt*128 + (mt*2+kc)
//             -> all 8 nt of one (mt,kc) share XCD (bid mod 8 invariant in nt)
// [1536,1664): base GEMM 64x64, K=256
__global__ __launch_bounds__(256) void k2_kernel(const bf16* __restrict__ Amat,
                                                 const bf16* __restrict__ SWb,
                                                 const bf16* __restrict__ Sm,
                                                 const bf16* __restrict__ BWb,
                                                 const float* __restrict__ Xn2,
                                                 const unsigned int* __restrict__ roT,
                                                 const unsigned short* __restrict__ wnT,
                                                 unsigned short* __restrict__ P0,
                                                 unsigned short* __restrict__ P1,
                                                 float* __restrict__ out) {
    __shared__ alignas(16) char smem[16384];
    int bid = blockIdx.x, tid = threadIdx.x;

    if (bid < 512) {
        // ---- DoG role ------------------------------------------------------
        int dt = bid & 7, t0 = (bid >> 3) * 16;
        float* xs_ = (float*)smem;         // [16][256]
        #pragma unroll
        for (int p = 0; p < 4; p++) {
            int flat = p * 1024 + tid * 4;
            *(float4*)&xs_[flat] = *(const float4*)&Xn2[(size_t)t0 * DIN + flat];
        }
        __syncthreads();

        int dl = tid & 63, tg = tid >> 6;   // 4 t per lane
        int dout = dt * 64 + dl;
        const float kC = -0.5f * LOG2E;
        float acc[4] = {0.f, 0.f, 0.f, 0.f};
        const unsigned int*   rop = roT + dout;
        const unsigned short* wnp = wnT + dout;

        for (int d = 0; d < DIN; d += 4) {
            float rr[4], oo[4], ww[4];
            #pragma unroll
            for (int k = 0; k < 4; k++) {
                unsigned int ro = rop[(d + k) * DOUT];
                rr[k] = frombits(ro << 16);
                oo[k] = frombits(ro & 0xFFFF0000u);
                ww[k] = frombits(((unsigned int)wnp[(d + k) * DOUT]) << 16);
            }
            #pragma unroll
            for (int j = 0; j < 4; j++) {   // t = tg*4 + j
                float4 xv = *(const float4*)&xs_[(tg * 4 + j) * DIN + d]; // broadcast
                float xs4[4] = {xv.x, xv.y, xv.z, xv.w};
                #pragma unroll
                for (int k = 0; k < 4; k++) {
                    float z = fmaf(xs4[k], rr[k], oo[k]);
                    float e = __builtin_amdgcn_exp2f(z * z * kC);
                    acc[j] = fmaf(z * e, ww[k], acc[j]);
                }
            }
        }
        size_t base = (size_t)2 * Tn * DOUT + (size_t)(t0 + tg * 4) * DOUT + dout;
        #pragma unroll
        for (int j = 0; j < 4; j++) out[base + (size_t)j * DOUT] = acc[j];
    } else if (bid < 1536) {
        // ---- spline GEMM role (split-K=2, XCD-aligned) ---------------------
        int idx = bid - 512;
        int nt = idx >> 7;                   // slow dim: stride 128 == 0 mod 8
        int rem = idx & 127;
        int mt = rem >> 1, kc = rem & 1;
        int row0 = mt * 64, col0 = nt * 64;
        floatx4 acc[2][2];
        #pragma unroll
        for (int r = 0; r < 2; r++)
            #pragma unroll
            for (int c = 0; c < 2; c++) acc[r][c] = (floatx4)(0.0f);
        gemm_core<KSP>((const short*)Amat, (const short*)SWb,
                       row0, col0, kc * 1024, 32, tid, smem, acc);
        unsigned short* P = kc ? P1 : P0;
        int wv = tid >> 6, lane = tid & 63;
        int m = lane & 15, q = lane >> 4;
        int wr = wv >> 1, wc = wv & 1;
        #pragma unroll
        for (int r = 0; r < 2; r++)
            #pragma unroll
            for (int c = 0; c < 2; c++)
                #pragma unroll
                for (int rr = 0; rr < 4; rr++) {
                    int row = row0 + wr * 32 + r * 16 + q * 4 + rr;
                    int col = col0 + wc * 32 + c * 16 + m;
                    P[(size_t)row * DOUT + col] =
                        (unsigned short)bf16bits(acc[r][c][rr]);
                }
    } else {
        // ---- base GEMM role ------------------------------------------------
        int idx = bid - 1536;
        int mt = idx >> 3, nt = idx & 7;
        int row0 = mt * 64, col0 = nt * 64;
        floatx4 acc[2][2];
        #pragma unroll
        for (int r = 0; r < 2; r++)
            #pragma unroll
            for (int c = 0; c < 2; c++) acc[r][c] = (floatx4)(0.0f);
        gemm_core<DIN>((const short*)Sm, (const short*)BWb,
                       row0, col0, 0, 8, tid, smem, acc);
        int wv = tid >> 6, lane = tid & 63;
        int m = lane & 15, q = lane >> 4;
        int wr = wv >> 1, wc = wv & 1;
        #pragma unroll
        for (int r = 0; r < 2; r++)
            #pragma unroll
            for (int c = 0; c < 2; c++)
                #pragma unroll
                for (int rr = 0; rr < 4; rr++) {
                    int row = row0 + wr * 32 + r * 16 + q * 4 + rr;
                    int col = col0 + wc * 32 + c * 16 + m;
                    out[((size_t)3 * Tn + row) * DOUT + col] = acc[r][c][rr];
                }
    }
}

// ================= K3: split-K reduce (bf16 P0+P1 -> f32 out) ================
__global__ __launch_bounds__(256) void k3_kernel(const unsigned short* __restrict__ P0,
                                                 const unsigned short* __restrict__ P1,
                                                 float* __restrict__ out) {
    int t8 = blockIdx.x * 256 + threadIdx.x;    // [0, 262144): 8 elems each
    size_t e = (size_t)t8 * 8;
    int row = (int)(e >> 9), col = (int)(e & 511);
    int which = row >> 10, t = row & 1023;
    int batch = (which == 0) ? 0 : (which == 1) ? 1 : (which == 2) ? 4 : 5;
    short8 a = *(const short8*)(P0 + e);
    short8 b = *(const short8*)(P1 + e);
    float4 o0, o1;
    float* po0 = (float*)&o0;
    float* po1 = (float*)&o1;
    #pragma unroll
    for (int j = 0; j < 4; j++) {
        po0[j] = frombits(((unsigned int)(unsigned short)a[j]) << 16)
               + frombits(((unsigned int)(unsigned short)b[j]) << 16);
        po1[j] = frombits(((unsigned int)(unsigned short)a[j + 4]) << 16)
               + frombits(((unsigned int)(unsigned short)b[j + 4]) << 16);
    }
    float* dst = &out[((size_t)batch * Tn + t) * DOUT + col];
    *(float4*)dst = o0;
    *(float4*)(dst + 4) = o1;
}

extern "C" void kernel_launch(void* const* d_in, const int* in_sizes, int n_in,
                              void* d_out, int out_size, void* d_ws, size_t ws_size,
                              hipStream_t stream) {
    const float* X        = (const float*)d_in[0];
    const float* ln_w     = (const float*)d_in[1];
    const float* ln_b     = (const float*)d_in[2];
    const float* base_w   = (const float*)d_in[3];
    const float* spline_w = (const float*)d_in[4];
    const float* scale    = (const float*)d_in[5];
    const float* transl   = (const float*)d_in[6];
    const float* grid_rbf = (const float*)d_in[7];
    const float* grid_bs  = (const float*)d_in[8];
    float* out = (float*)d_out;

    char* ws = (char*)d_ws;
    bf16*  Amat = (bf16*)ws;                                   // 16 MiB   [4096][2048]
    bf16*  SWb  = (bf16*)(ws + 16777216);                      // 2 MiB    [512][2048]
    bf16*  BWb  = (bf16*)(ws + 18874368);                      // 0.25 MiB [512][256]
    bf16*  Sm   = (bf16*)(ws + 19136512);                      // 0.5 MiB  [1024][256]
    float* Xn2  = (float*)(ws + 19660800);                     // 1 MiB    [1024][256]
    unsigned int*   roT = (unsigned int*)(ws + 20709376);      // 0.5 MiB  [256][512]
    unsigned short* wnT = (unsigned short*)(ws + 21233664);    // 0.25 MiB [256][512]
    unsigned short* P0  = (unsigned short*)(ws + 22282240);    // 4 MiB    [4096][512]
    unsigned short* P1  = (unsigned short*)(ws + 26476544);    // 4 MiB

    k1_kernel<<<2240, 256, 0, stream>>>(X, ln_w, ln_b, grid_rbf, grid_bs,
                                        spline_w, base_w, scale, transl,
                                        Amat, Sm, Xn2, SWb, BWb, roT, wnT);
    k2_kernel<<<1664, 256, 0, stream>>>(Amat, SWb, Sm, BWb, Xn2, roT, wnT,
                                        P0, P1, out);
    k3_kernel<<<1024, 256, 0, stream>>>(P0, P1, out);
}

// Round 12
// 121.744 us; speedup vs baseline: 1.4544x; 1.0511x over previous
//
#include <hip/hip_runtime.h>
#include <hip/hip_bf16.h>

// FC_KANLayer: B=6, T=1024, D_IN=256, D_OUT=512, NUM_GRIDS=8
// FUNC_LIST = [rbf, bs, dog, base, rbf, bs]
// f32 in/out; GEMMs via bf16 MFMA.
// R12 = R11 + dog restructure: 256 unique dout/block (zero param redundancy),
// exp-scale folded into params (5-op inner chain), d-loop x8 batched loads.

typedef short short8 __attribute__((ext_vector_type(8)));
typedef float floatx4 __attribute__((ext_vector_type(4)));

using bf16 = __hip_bfloat16;

#define LOG2E 1.44269504088896340736f
// c = sqrt(0.5*log2(e)); exp(-0.5 x^2) = exp2(-(c x)^2)
#define DOG_C  0.84932180028801904f
#define DOG_IC 1.17741002251547466f   // 1/c

constexpr int Tn   = 1024;
constexpr int DIN  = 256;
constexpr int DOUT = 512;
constexpr int NG   = 8;
constexpr int KSP  = DIN * NG;            // 2048
constexpr float INV_DENOM = 7.0f / 3.0f;  // 1/DENOM, DENOM = 3/7

__device__ __forceinline__ unsigned int bf16bits(float v) {
    return (unsigned int)__builtin_bit_cast(unsigned short, __float2bfloat16(v));
}
__device__ __forceinline__ float frombits(unsigned int u) {
    return __builtin_bit_cast(float, u);
}

// ================= K1 ========================================================
// [0,1536): LN+basis wave-per-row | [1536,2112): f32->bf16 convert (x8 vec)
// [2112,2240): dog-param transpose-pack (pre-scaled by DOG_C), 32x32 tiles
__global__ __launch_bounds__(256) void k1_kernel(
        const float* __restrict__ X,
        const float* __restrict__ w,
        const float* __restrict__ b,
        const float* __restrict__ grid_rbf,
        const float* __restrict__ grid_bs,
        const float* __restrict__ sw,
        const float* __restrict__ bw,
        const float* __restrict__ sc,
        const float* __restrict__ tr,
        bf16* __restrict__ Amat,            // [4096][2048]
        bf16* __restrict__ Sm,              // [1024][256]
        float* __restrict__ Xn2,            // [1024][256]
        bf16* __restrict__ swb,             // [512][2048]
        bf16* __restrict__ bwb,             // [512][256]
        unsigned int* __restrict__ roT,     // [256][512] packed bf16 (c/s, -c*t/s)
        unsigned short* __restrict__ wnT) { // [256][512] bf16 (-bw/c)
    __shared__ float u1[32][33], u2[32][33];
    int tid = threadIdx.x, bid = blockIdx.x;

    if (bid >= 2112) {
        // ---- transpose-pack role (pre-scaled) ------------------------------
        int tb = bid - 2112;                  // 0..127
        int dout0 = (tb >> 3) * 32, din0 = (tb & 7) * 32;
        #pragma unroll
        for (int p = 0; p < 4; p++) {
            int idx = p * 256 + tid;
            int r = idx >> 5, c = idx & 31;
            float vs = sc[(dout0 + r) * DIN + din0 + c];
            float vt = tr[(dout0 + r) * DIN + din0 + c];
            float vb = bw[(dout0 + r) * DIN + din0 + c];
            float inv = DOG_C / vs;
            unsigned int packed = bf16bits(inv) | (bf16bits(-vt * inv) << 16);
            u1[r][c] = __builtin_bit_cast(float, packed);
            u2[r][c] = -vb * DOG_IC;
        }
        __syncthreads();
        #pragma unroll
        for (int p = 0; p < 4; p++) {
            int idx = p * 256 + tid;
            int c = idx >> 5, r = idx & 31;   // consecutive tid -> consecutive r
            roT[(din0 + c) * DOUT + dout0 + r] = __builtin_bit_cast(unsigned int, u1[r][c]);
            wnT[(din0 + c) * DOUT + dout0 + r] = (unsigned short)bf16bits(u2[r][c]);
        }
        return;
    }
    if (bid >= 1536) {
        // ---- convert role ---------------------------------------------------
        int e = ((bid - 1536) * 256 + tid) * 8;    // [0, 1179648)
        const float* src = (e < 1048576) ? (sw + e) : (bw + (e - 1048576));
        bf16* dst = (e < 1048576) ? (swb + e) : (bwb + (e - 1048576));
        float4 v0 = *(const float4*)src;
        float4 v1 = *(const float4*)(src + 4);
        short8 p;
        p[0] = __builtin_bit_cast(short, __float2bfloat16(v0.x));
        p[1] = __builtin_bit_cast(short, __float2bfloat16(v0.y));
        p[2] = __builtin_bit_cast(short, __float2bfloat16(v0.z));
        p[3] = __builtin_bit_cast(short, __float2bfloat16(v0.w));
        p[4] = __builtin_bit_cast(short, __float2bfloat16(v1.x));
        p[5] = __builtin_bit_cast(short, __float2bfloat16(v1.y));
        p[6] = __builtin_bit_cast(short, __float2bfloat16(v1.z));
        p[7] = __builtin_bit_cast(short, __float2bfloat16(v1.w));
        *(short8*)dst = p;
        return;
    }

    // ---- LN + basis role ----------------------------------------------------
    int wv = tid >> 6, lane = tid & 63;
    int row = bid * 4 + wv;              // b*1024 + t
    int batch = row >> 10, t = row & 1023;

    float x[4];
    #pragma unroll
    for (int j = 0; j < 4; j++) x[j] = X[(size_t)row * DIN + j * 64 + lane];
    float s = x[0] + x[1] + x[2] + x[3];
    float ss = x[0] * x[0] + x[1] * x[1] + x[2] * x[2] + x[3] * x[3];
    #pragma unroll
    for (int o = 1; o < 64; o <<= 1) {
        s  += __shfl_xor(s, o);
        ss += __shfl_xor(ss, o);
    }
    float mu = s * (1.0f / DIN);
    float rstd = rsqrtf(ss * (1.0f / DIN) - mu * mu + 1e-5f);

    float xn[4];
    #pragma unroll
    for (int j = 0; j < 4; j++) {
        int din = j * 64 + lane;
        xn[j] = (x[j] - mu) * rstd * w[din] + b[din];
    }

    if (batch == 2) {
        #pragma unroll
        for (int j = 0; j < 4; j++)
            Xn2[(size_t)t * DIN + j * 64 + lane] = xn[j];
    } else if (batch == 3) {
        #pragma unroll
        for (int j = 0; j < 4; j++) {
            float e = __builtin_amdgcn_exp2f(-xn[j] * LOG2E);
            float si = xn[j] * __builtin_amdgcn_rcpf(1.0f + e);
            Sm[(size_t)t * DIN + j * 64 + lane] = __float2bfloat16(si);
        }
    } else {
        int which = (batch == 0) ? 0 : (batch == 1) ? 1 : (batch == 4) ? 2 : 3;
        bool is_rbf = (batch == 0) || (batch == 4);
        #pragma unroll
        for (int j = 0; j < 4; j++) {
            float v = xn[j];
            float outv[NG];
            if (is_rbf) {
                #pragma unroll
                for (int g = 0; g < NG; g++) {
                    float d = (v - grid_rbf[g]) * INV_DENOM;
                    outv[g] = __builtin_amdgcn_exp2f(-d * d * LOG2E);
                }
            } else {
                float g[12];
                #pragma unroll
                for (int i = 0; i < 12; i++) g[i] = grid_bs[i];
                float ih = 1.0f / (g[1] - g[0]);
                float ihk[3] = {ih, ih * 0.5f, ih * (1.0f / 3.0f)};
                float bs_[11];
                #pragma unroll
                for (int i = 0; i < 11; i++)
                    bs_[i] = (v >= g[i] && v < g[i + 1]) ? 1.0f : 0.0f;
                #pragma unroll
                for (int k = 1; k <= 3; k++) {
                    float rk = ihk[k - 1];
                    #pragma unroll
                    for (int i = 0; i < 10; i++) {
                        if (i <= 10 - k) {
                            bs_[i] = (v - g[i]) * rk * bs_[i]
                                   + (g[i + k + 1] - v) * rk * bs_[i + 1];
                        }
                    }
                }
                #pragma unroll
                for (int gg = 0; gg < NG; gg++) outv[gg] = bs_[gg];
            }
            short8 pv;
            #pragma unroll
            for (int gg = 0; gg < NG; gg++)
                pv[gg] = __builtin_bit_cast(short, __float2bfloat16(outv[gg]));
            *(short8*)((short*)Amat + (size_t)(which * Tn + t) * KSP
                       + (size_t)(j * 64 + lane) * NG) = pv;
        }
    }
}

// ---------------- GEMM core: 64x64 tile, BK=32, dbuf LDS, XOR-swizzled -------
template <int KS>
__device__ __forceinline__ void gemm_core(const short* __restrict__ A,
                                          const short* __restrict__ Bw,
                                          int row0, int col0, int kbase, int iters,
                                          int tid, char* smem, floatx4 acc[2][2]) {
    short* ldsA = (short*)smem;            // [2][64][32] = 8 KiB
    short* ldsB = (short*)(smem + 8192);   // [2][64][32] = 8 KiB
    int wv = tid >> 6, lane = tid & 63;
    int r16 = lane >> 2, cs = lane & 3;
    int cg = cs ^ ((r16 >> 1) & 3);
    const short* gA = A  + (size_t)(row0 + wv * 16 + r16) * KS + kbase + cg * 8;
    const short* gB = Bw + (size_t)(col0 + wv * 16 + r16) * KS + kbase + cg * 8;

    int m = lane & 15, q = lane >> 4;
    int wr = wv >> 1, wc = wv & 1;
    int ra0 = wr * 32 + m, ra1 = ra0 + 16;
    int rb0 = wc * 32 + m, rb1 = rb0 + 16;
    int oA0 = ra0 * 32 + (q ^ ((ra0 >> 1) & 3)) * 8;
    int oA1 = ra1 * 32 + (q ^ ((ra1 >> 1) & 3)) * 8;
    int oB0 = rb0 * 32 + (q ^ ((rb0 >> 1) & 3)) * 8;
    int oB1 = rb1 * 32 + (q ^ ((rb1 >> 1) & 3)) * 8;

    __builtin_amdgcn_global_load_lds(
        (const __attribute__((address_space(1))) void*)gA,
        (__attribute__((address_space(3))) void*)(ldsA + wv * 512), 16, 0, 0);
    __builtin_amdgcn_global_load_lds(
        (const __attribute__((address_space(1))) void*)gB,
        (__attribute__((address_space(3))) void*)(ldsB + wv * 512), 16, 0, 0);

    for (int i = 0; i < iters; i++) {
        int cur = i & 1;
        __syncthreads();
        if (i + 1 < iters) {
            int nxt = cur ^ 1, kof = (i + 1) * 32;
            __builtin_amdgcn_global_load_lds(
                (const __attribute__((address_space(1))) void*)(gA + kof),
                (__attribute__((address_space(3))) void*)(ldsA + nxt * 2048 + wv * 512),
                16, 0, 0);
            __builtin_amdgcn_global_load_lds(
                (const __attribute__((address_space(1))) void*)(gB + kof),
                (__attribute__((address_space(3))) void*)(ldsB + nxt * 2048 + wv * 512),
                16, 0, 0);
        }
        const short* bA = ldsA + cur * 2048;
        const short* bB = ldsB + cur * 2048;
        short8 a0 = *(const short8*)(bA + oA0);
        short8 a1 = *(const short8*)(bA + oA1);
        short8 b0 = *(const short8*)(bB + oB0);
        short8 b1 = *(const short8*)(bB + oB1);
        acc[0][0] = __builtin_amdgcn_mfma_f32_16x16x32_bf16(a0, b0, acc[0][0], 0, 0, 0);
        acc[0][1] = __builtin_amdgcn_mfma_f32_16x16x32_bf16(a0, b1, acc[0][1], 0, 0, 0);
        acc[1][0] = __builtin_amdgcn_mfma_f32_16x16x32_bf16(a1, b0, acc[1][0], 0, 0, 0);
        acc[1][1] = __builtin_amdgcn_mfma_f32_16x16x32_bf16(a1, b1, acc[1][1], 0, 0, 0);
    }
}

// ================= K2: heterogeneous mega-kernel =============================
// [0,512):    DoG: block = 256 unique dout (dt=bid&1) x 4 t; zero param redundancy
// [512,1536): spline GEMM 64x64 split-K=2; bid = 512 + nt*128 + (mt*2+kc)
// [1536,1664): base GEMM 64x64, K=256
__global__ __launch_bounds__(256) void k2_kernel(const bf16* __restrict__ Amat,
                                                 const bf16* __restrict__ SWb,
                                                 const bf16* __restrict__ Sm,
                                                 const bf16* __restrict__ BWb,
                                                 const float* __restrict__ Xn2,
                                                 const unsigned int* __restrict__ roT,
                                                 const unsigned short* __restrict__ wnT,
                                                 unsigned short* __restrict__ P0,
                                                 unsigned short* __restrict__ P1,
                                                 float* __restrict__ out) {
    __shared__ alignas(16) char smem[16384];
    int bid = blockIdx.x, tid = threadIdx.x;

    if (bid < 512) {
        // ---- DoG role: 256 dout x 4 t --------------------------------------
        int dt = bid & 1, t0 = (bid >> 1) * 4;
        float* xs_ = (float*)smem;          // [4][256] = 4 KiB
        *(float4*)&xs_[tid * 4] = *(const float4*)&Xn2[(size_t)t0 * DIN + tid * 4];
        __syncthreads();

        int dout = dt * 256 + tid;
        float acc[4] = {0.f, 0.f, 0.f, 0.f};
        const unsigned int*   rop = roT + dout;
        const unsigned short* wnp = wnT + dout;

        for (int d = 0; d < DIN; d += 8) {
            unsigned int ro[8]; unsigned short wn[8];
            #pragma unroll
            for (int k = 0; k < 8; k++) {
                ro[k] = rop[(d + k) * DOUT];
                wn[k] = wnp[(d + k) * DOUT];
            }
            #pragma unroll
            for (int g = 0; g < 2; g++) {
                float4 xv[4];
                #pragma unroll
                for (int j = 0; j < 4; j++)
                    xv[j] = *(const float4*)&xs_[j * DIN + d + g * 4];  // broadcast
                #pragma unroll
                for (int k = 0; k < 4; k++) {
                    int kk = g * 4 + k;
                    float r = frombits(ro[kk] << 16);
                    float o = frombits(ro[kk] & 0xFFFF0000u);
                    float w = frombits(((unsigned int)wn[kk]) << 16);
                    const float* xp = (const float*)&xv[0];
                    #pragma unroll
                    for (int j = 0; j < 4; j++) {
                        float xval = ((const float*)&xv[j])[k];
                        float z = fmaf(xval, r, o);
                        float e = __builtin_amdgcn_exp2f(-(z * z));
                        acc[j] = fmaf(z * e, w, acc[j]);
                    }
                    (void)xp;
                }
            }
        }
        size_t base = (size_t)2 * Tn * DOUT + (size_t)t0 * DOUT + dout;
        #pragma unroll
        for (int j = 0; j < 4; j++) out[base + (size_t)j * DOUT] = acc[j];
    } else if (bid < 1536) {
        // ---- spline GEMM role (split-K=2, XCD-aligned) ---------------------
        int idx = bid - 512;
        int nt = idx >> 7;                   // slow dim: stride 128 == 0 mod 8
        int rem = idx & 127;
        int mt = rem >> 1, kc = rem & 1;
        int row0 = mt * 64, col0 = nt * 64;
        floatx4 acc[2][2];
        #pragma unroll
        for (int r = 0; r < 2; r++)
            #pragma unroll
            for (int c = 0; c < 2; c++) acc[r][c] = (floatx4)(0.0f);
        gemm_core<KSP>((const short*)Amat, (const short*)SWb,
                       row0, col0, kc * 1024, 32, tid, smem, acc);
        unsigned short* P = kc ? P1 : P0;
        int wv = tid >> 6, lane = tid & 63;
        int m = lane & 15, q = lane >> 4;
        int wr = wv >> 1, wc = wv & 1;
        #pragma unroll
        for (int r = 0; r < 2; r++)
            #pragma unroll
            for (int c = 0; c < 2; c++)
                #pragma unroll
                for (int rr = 0; rr < 4; rr++) {
                    int row = row0 + wr * 32 + r * 16 + q * 4 + rr;
                    int col = col0 + wc * 32 + c * 16 + m;
                    P[(size_t)row * DOUT + col] =
                        (unsigned short)bf16bits(acc[r][c][rr]);
                }
    } else {
        // ---- base GEMM role ------------------------------------------------
        int idx = bid - 1536;
        int mt = idx >> 3, nt = idx & 7;
        int row0 = mt * 64, col0 = nt * 64;
        floatx4 acc[2][2];
        #pragma unroll
        for (int r = 0; r < 2; r++)
            #pragma unroll
            for (int c = 0; c < 2; c++) acc[r][c] = (floatx4)(0.0f);
        gemm_core<DIN>((const short*)Sm, (const short*)BWb,
                       row0, col0, 0, 8, tid, smem, acc);
        int wv = tid >> 6, lane = tid & 63;
        int m = lane & 15, q = lane >> 4;
        int wr = wv >> 1, wc = wv & 1;
        #pragma unroll
        for (int r = 0; r < 2; r++)
            #pragma unroll
            for (int c = 0; c < 2; c++)
                #pragma unroll
                for (int rr = 0; rr < 4; rr++) {
                    int row = row0 + wr * 32 + r * 16 + q * 4 + rr;
                    int col = col0 + wc * 32 + c * 16 + m;
                    out[((size_t)3 * Tn + row) * DOUT + col] = acc[r][c][rr];
                }
    }
}

// ================= K3: split-K reduce (bf16 P0+P1 -> f32 out) ================
__global__ __launch_bounds__(256) void k3_kernel(const unsigned short* __restrict__ P0,
                                                 const unsigned short* __restrict__ P1,
                                                 float* __restrict__ out) {
    int t8 = blockIdx.x * 256 + threadIdx.x;    // [0, 262144): 8 elems each
    size_t e = (size_t)t8 * 8;
    int row = (int)(e >> 9), col = (int)(e & 511);
    int which = row >> 10, t = row & 1023;
    int batch = (which == 0) ? 0 : (which == 1) ? 1 : (which == 2) ? 4 : 5;
    short8 a = *(const short8*)(P0 + e);
    short8 b = *(const short8*)(P1 + e);
    float4 o0, o1;
    float* po0 = (float*)&o0;
    float* po1 = (float*)&o1;
    #pragma unroll
    for (int j = 0; j < 4; j++) {
        po0[j] = frombits(((unsigned int)(unsigned short)a[j]) << 16)
               + frombits(((unsigned int)(unsigned short)b[j]) << 16);
        po1[j] = frombits(((unsigned int)(unsigned short)a[j + 4]) << 16)
               + frombits(((unsigned int)(unsigned short)b[j + 4]) << 16);
    }
    float* dst = &out[((size_t)batch * Tn + t) * DOUT + col];
    *(float4*)dst = o0;
    *(float4*)(dst + 4) = o1;
}

extern "C" void kernel_launch(void* const* d_in, const int* in_sizes, int n_in,
                              void* d_out, int out_size, void* d_ws, size_t ws_size,
                              hipStream_t stream) {
    const float* X        = (const float*)d_in[0];
    const float* ln_w     = (const float*)d_in[1];
    const float* ln_b     = (const float*)d_in[2];
    const float* base_w   = (const float*)d_in[3];
    const float* spline_w = (const float*)d_in[4];
    const float* scale    = (const float*)d_in[5];
    const float* transl   = (const float*)d_in[6];
    const float* grid_rbf = (const float*)d_in[7];
    const float* grid_bs  = (const float*)d_in[8];
    float* out = (float*)d_out;

    char* ws = (char*)d_ws;
    bf16*  Amat = (bf16*)ws;                                   // 16 MiB   [4096][2048]
    bf16*  SWb  = (bf16*)(ws + 16777216);                      // 2 MiB    [512][2048]
    bf16*  BWb  = (bf16*)(ws + 18874368);                      // 0.25 MiB [512][256]
    bf16*  Sm   = (bf16*)(ws + 19136512);                      // 0.5 MiB  [1024][256]
    float* Xn2  = (float*)(ws + 19660800);                     // 1 MiB    [1024][256]
    unsigned int*   roT = (unsigned int*)(ws + 20709376);      // 0.5 MiB  [256][512]
    unsigned short* wnT = (unsigned short*)(ws + 21233664);    // 0.25 MiB [256][512]
    unsigned short* P0  = (unsigned short*)(ws + 22282240);    // 4 MiB    [4096][512]
    unsigned short* P1  = (unsigned short*)(ws + 26476544);    // 4 MiB

    k1_kernel<<<2240, 256, 0, stream>>>(X, ln_w, ln_b, grid_rbf, grid_bs,
                                        spline_w, base_w, scale, transl,
                                        Amat, Sm, Xn2, SWb, BWb, roT, wnT);
    k2_kernel<<<1664, 256, 0, stream>>>(Amat, SWb, Sm, BWb, Xn2, roT, wnT,
                                        P0, P1, out);
    k3_kernel<<<1024, 256, 0, stream>>>(P0, P1, out);
}